// Round 3
// baseline (332.935 us; speedup 1.0000x reference)
//
#include <hip/hip_runtime.h>

// CostVolume via bf16 MFMA Gram band: cost[b,d,h,w] = (1/64)·G[w][w-d],
// G = L^T·R per (b,h), banded (0 <= d < 48). B=4 C=64 H=256 W=512 D=48.
//
// Round-6: software-pipelined persistent blocks (r2 counters showed the
// barrier-drain structure capped load duty cycle at ~10%: all pipes idle,
// HBM pinned at 1.85 TB/s regardless of occupancy/conflict fixes).
//  * Each block owns (w-tile, 4 h-rows, b): 8 stages (4h x 2 c-chunks).
//    grid = 4 x 64 x 4 = 1024 = exactly 4 resident blocks per CU (LDS
//    2 x 19456 = 38912 B), zero tail.
//  * Pipeline: pack(s)->LDS buf[s&1]; ISSUE loads(s+1); barrier;
//    compute(s); [epilogue when h completes]. Stage-s+1 global loads stay
//    in flight across pack/barrier/MFMA/epilogue (T14) -- duty ~70%.
//  * Epilogue scratch aliases buf1 (the buffer consumed right before each
//    epilogue; next write to buf1 is 2 barriers later -- race-safe).
//  * Fragment path / rowswz / f2bf2 numerics / full-line NT stores
//    identical to the round-2-verified kernel.

#define BB 4
#define CC 64
#define HH 256
#define WW 512
#define DD 48
#define TW 128
#define CK 32          // channel chunk (= MFMA K)
#define RWIN 176       // right window cols: w0-48 .. w0+127
#define WR 32          // shorts per LDS row (64 B)
#define ST 129         // epilogue scratch row stride (fp32)
#define NT 256
#define H_PER 4
#define NSTAGE (2 * H_PER)
#define BUFSH ((TW + RWIN) * WR)   // shorts per LDS buffer

typedef short bf16x8 __attribute__((ext_vector_type(8)));
typedef float f32x4  __attribute__((ext_vector_type(4)));

// fp32 -> bf16 round-to-nearest-even, packed pair (lo in bits 15:0)
__device__ __forceinline__ unsigned int f2bf2(float lo, float hi) {
  unsigned int a = __float_as_uint(lo);
  unsigned int b = __float_as_uint(hi);
  a = (a + 0x7fffu + ((a >> 16) & 1u)) >> 16;
  b = (b + 0x7fffu + ((b >> 16) & 1u)) & 0xffff0000u;
  return a | b;
}

// physical LDS row: mix w bit2 into bit0 (staging-write bank spread;
// read side compensates with xb = (n16>>2)&1)
__device__ __forceinline__ int rowswz(int w) { return w ^ ((w >> 2) & 1); }

__global__ __launch_bounds__(NT, 4)
void cost_volume_mfma(const float* __restrict__ left,
                      const float* __restrict__ right,
                      float* __restrict__ out) {
  __shared__ __align__(16) char smem[2 * BUFSH * 2];
  unsigned short* sb0 = reinterpret_cast<unsigned short*>(smem);
  unsigned short* sb1 = sb0 + BUFSH;
  float*          scr = reinterpret_cast<float*>(sb1);  // epilogue scratch

  const int w0   = blockIdx.x * TW;     // 0,128,256,384
  const int h0   = blockIdx.y * H_PER;  // 0..252 step 4
  const int b    = blockIdx.z;
  const int tid  = threadIdx.x;
  const int lane = tid & 63;
  const int wv   = tid >> 6;            // wave 0..3
  const int n16  = lane & 15;
  const int q    = lane >> 4;
  const int xb   = (n16 >> 2) & 1;      // read-side row-swizzle bit

  const size_t HWs    = (size_t)HH * WW;
  const size_t bplane = (size_t)b * CC * HWs;

  // staging task coords: c-quad from low lane bits (bank spread),
  // w-quad from high bits (8 lanes per 128B line, fully coalesced)
  const int scq4 = 4 * (tid & 7);     // 0..28
  const int swq4 = 4 * (tid >> 3);    // 0..124
  const int g4a  = w0 - 48 + swq4;    // right-window global col (rep 0)
  const bool mact = (tid < 96);       // rep-1 margin task active

  f32x4 acc[2][4];
  #pragma unroll
  for (int i = 0; i < 2; ++i)
    #pragma unroll
    for (int t = 0; t < 4; ++t)
      acc[i][t] = (f32x4){0.f, 0.f, 0.f, 0.f};

  // stage-(s) register buffer (single named set: pack(s) consumes, then
  // ISSUE(s+1) overwrites -- all indices compile-time)
  f32x4 vL[4], vRa[4], vRb[4];

  // ---- ISSUE: global loads for stage s into registers
  auto ISSUE = [&](int s) {
    const int hh = h0 + (s >> 1);
    const int c0 = (s & 1) * CK;
    const size_t rbase = bplane + (size_t)hh * WW;
    #pragma unroll
    for (int r = 0; r < 4; ++r)
      vL[r] = *reinterpret_cast<const f32x4*>(
          left + rbase + (size_t)(c0 + scq4 + r) * HWs + w0 + swq4);
    if (g4a >= 0) {
      #pragma unroll
      for (int r = 0; r < 4; ++r)
        vRa[r] = *reinterpret_cast<const f32x4*>(
            right + rbase + (size_t)(c0 + scq4 + r) * HWs + g4a);
    } else {
      #pragma unroll
      for (int r = 0; r < 4; ++r) vRa[r] = (f32x4){0.f, 0.f, 0.f, 0.f};
    }
    if (mact) {
      #pragma unroll
      for (int r = 0; r < 4; ++r)
        vRb[r] = *reinterpret_cast<const f32x4*>(
            right + rbase + (size_t)(c0 + scq4 + r) * HWs + (g4a + 128));
    }
  };

  ISSUE(0);

  #pragma unroll 1
  for (int s = 0; s < NSTAGE; ++s) {
    unsigned short* sbL = (s & 1) ? sb1 : sb0;   // [w][c], 128 rows
    unsigned short* sbR = sbL + TW * WR;         // [w'][c], 176 rows

    // ---- PACK stage s into LDS (drains stage-s loads)
    #pragma unroll
    for (int j = 0; j < 4; ++j) {
      uint2 pk;
      pk.x = f2bf2(vL[0][j], vL[1][j]);
      pk.y = f2bf2(vL[2][j], vL[3][j]);
      *reinterpret_cast<uint2*>(&sbL[rowswz(swq4 + j) * WR + scq4]) = pk;
    }
    #pragma unroll
    for (int j = 0; j < 4; ++j) {
      uint2 pk;
      pk.x = f2bf2(vRa[0][j], vRa[1][j]);
      pk.y = f2bf2(vRa[2][j], vRa[3][j]);
      *reinterpret_cast<uint2*>(&sbR[rowswz(swq4 + j) * WR + scq4]) = pk;
    }
    if (mact) {
      #pragma unroll
      for (int j = 0; j < 4; ++j) {
        uint2 pk;
        pk.x = f2bf2(vRb[0][j], vRb[1][j]);
        pk.y = f2bf2(vRb[2][j], vRb[3][j]);
        *reinterpret_cast<uint2*>(&sbR[rowswz(swq4 + 128 + j) * WR + scq4]) = pk;
      }
    }

    // ---- issue next stage's loads (in flight across barrier+compute+epi)
    if (s + 1 < NSTAGE) ISSUE(s + 1);

    __syncthreads();

    // ---- compute: one ds_read_b128 per fragment
    #pragma unroll
    for (int i = 0; i < 2; ++i) {
      const int u0 = 16 * (wv + 4 * i);
      const bf16x8 A = *reinterpret_cast<const bf16x8*>(
          &sbL[((u0 + n16) ^ xb) * WR + 8 * q]);
      #pragma unroll
      for (int t = 0; t < 4; ++t) {
        const int rB = u0 + 16 * t + n16;   // sR row = v_global - w0 + 48
        const bf16x8 Bv = *reinterpret_cast<const bf16x8*>(
            &sbR[(rB ^ xb) * WR + 8 * q]);
        acc[i][t] =
            __builtin_amdgcn_mfma_f32_16x16x32_bf16(A, Bv, acc[i][t], 0, 0, 0);
      }
    }

    if (s & 1) {
      // ---- epilogue for h = h0 + (s>>1): scratch aliases buf1 (just
      // consumed; next write to buf1 is 2 barriers away)
      __syncthreads();   // all waves done reading buf1
      const int hh = h0 + (s >> 1);
      const float scale = 1.0f / 64.0f;
      #pragma unroll 1
      for (int half = 0; half < 2; ++half) {
        const int dbase = 24 * half;
        if (half) __syncthreads();   // half-0 E2 reads done before overwrite
        // E1: scatter acc -> scr[d - dbase][u0 + m]
        #pragma unroll
        for (int i = 0; i < 2; ++i) {
          const int u0 = 16 * (wv + 4 * i);
          #pragma unroll
          for (int t = 0; t < 4; ++t)
            #pragma unroll
            for (int r = 0; r < 4; ++r) {
              const int m = 4 * q + r;
              const int d = m - n16 + 48 - 16 * t;
              const unsigned int dr = (unsigned int)(d - dbase);
              if (dr < 24u) scr[dr * ST + u0 + m] = acc[i][t][r] * scale;
            }
        }
        __syncthreads();
        // E2: full-line stores: 24 rows x 32 float4, non-temporal
        const size_t obase = (((size_t)b * DD + dbase) * HH + hh) * WW + w0;
        #pragma unroll
        for (int s3 = 0; s3 < 3; ++s3) {
          const int ss = tid + s3 * NT;
          const int dr = ss >> 5;
          const int p  = ss & 31;
          const f32x4 v = *reinterpret_cast<const f32x4*>(&scr[dr * ST + 4 * p]);
          __builtin_nontemporal_store(
              v, reinterpret_cast<f32x4*>(out + obase + (size_t)dr * HWs + 4 * p));
        }
      }
      // reset accumulators for next h
      #pragma unroll
      for (int i = 0; i < 2; ++i)
        #pragma unroll
        for (int t = 0; t < 4; ++t)
          acc[i][t] = (f32x4){0.f, 0.f, 0.f, 0.f};
    }
    // no trailing barrier needed: pack(s+1) targets the other buffer, and
    // the next stage's pre-compute barrier orders epilogue reads vs pack(s+2)
  }
}

extern "C" void kernel_launch(void* const* d_in, const int* in_sizes, int n_in,
                              void* d_out, int out_size, void* d_ws, size_t ws_size,
                              hipStream_t stream) {
  const float* left  = (const float*)d_in[0];
  const float* right = (const float*)d_in[1];
  float* out = (float*)d_out;

  dim3 grid(WW / TW, HH / H_PER, BB);   // 4 x 64 x 4 = 1024 blocks
  dim3 block(NT);
  cost_volume_mfma<<<grid, block, 0, stream>>>(left, right, out);
}